// Round 1
// baseline (230.914 us; speedup 1.0000x reference)
//
#include <hip/hip_runtime.h>
#include <math.h>

typedef float  f32x4  __attribute__((ext_vector_type(4)));
typedef short  bf16x8 __attribute__((ext_vector_type(8)));
typedef unsigned short u16x8 __attribute__((ext_vector_type(8)));

#define B_ROWS 2048
#define D_DIM  512
#define W_DIM  512
#define N_NODES 63
#define N_BINS  64
#define K_TOT   32768   // 64 * 512

__device__ __forceinline__ unsigned short f2bf(float f) {
    union { float f; unsigned int u; } v; v.f = f;
    unsigned int u = v.u;
    return (unsigned short)((u + 0x7fffu + ((u >> 16) & 1u)) >> 16);
}

__device__ __forceinline__ float sigmoidf_(float z) {
    return 1.0f / (1.0f + expf(-z));
}

// ---------------- kernel 1: distribution [2048,64] -------------------------
// one wave per row; lanes 0..62 compute node decisions, all 64 lanes then
// compute leaf products via shuffle gather through the idx table.
__global__ __launch_bounds__(256) void k_dist(
    const float* __restrict__ x, const float* __restrict__ ray,
    const float* __restrict__ w_i, const float* __restrict__ b_i,
    const float* __restrict__ a_i, const int* __restrict__ idx,
    float* __restrict__ dist)
{
    const int wid  = threadIdx.x >> 6;
    const int lane = threadIdx.x & 63;
    const int row  = blockIdx.x * 4 + wid;
    const float* xr = x + (size_t)row * D_DIM;

    float dotv = 0.f, xx = 0.f, rr = 0.f;
#pragma unroll
    for (int j = 0; j < 2; ++j) {
        f32x4 xv = *(const f32x4*)(xr  + j * 256 + lane * 4);
        f32x4 rv = *(const f32x4*)(ray + j * 256 + lane * 4);
        dotv += xv.x * rv.x + xv.y * rv.y + xv.z * rv.z + xv.w * rv.w;
        xx   += xv.x * xv.x + xv.y * xv.y + xv.z * xv.z + xv.w * xv.w;
        rr   += rv.x * rv.x + rv.y * rv.y + rv.z * rv.z + rv.w * rv.w;
    }
#pragma unroll
    for (int off = 1; off < 64; off <<= 1) {
        dotv += __shfl_xor(dotv, off, 64);
        xx   += __shfl_xor(xx,   off, 64);
        rr   += __shfl_xor(rr,   off, 64);
    }
    float xn = fmaxf(sqrtf(xx), 1e-8f);
    float rn = fmaxf(sqrtf(rr), 1e-8f);
    float cosv = dotv / (xn * rn);
    cosv = fminf(1.f, fmaxf(-1.f, cosv));
    float angle = acosf(cosv) * 0.31830988618379067f; // 1/pi

    float dec = 0.f;
    if (lane < N_NODES) {
        float sw = sigmoidf_(w_i[lane]);
        float sb = sigmoidf_(b_i[lane]);
        float nf = (0.5f + sw) * angle - sb;
        dec = sigmoidf_(nf * (1.0f + a_i[lane]));
    }

    float p = 1.f;
#pragma unroll
    for (int v = 0; v < 6; ++v) {
        int j = idx[lane * 6 + v];
        int node = (j < N_NODES) ? j : j - N_NODES;
        float d = __shfl(dec, node, 64);
        p *= (j < N_NODES) ? d : (1.0f - d);
    }
    dist[(size_t)row * N_BINS + lane] = p;
}

// ---------------- kernel 2: transpose T[64][512][512] f32 -> Tt[512][32768] bf16
__global__ __launch_bounds__(256) void k_transpose(
    const float* __restrict__ T, unsigned short* __restrict__ Tt)
{
    __shared__ float tile[32][33];
    const int l  = blockIdx.z;
    const int i0 = blockIdx.x * 32, w0 = blockIdx.y * 32;
    const int tx = threadIdx.x & 31, ty = threadIdx.x >> 5; // ty 0..7
    const float* src = T + ((size_t)(l * 512 + i0)) * 512 + w0;
#pragma unroll
    for (int r = 0; r < 4; ++r) {
        int i = ty + r * 8;
        tile[i][tx] = src[(size_t)i * 512 + tx];
    }
    __syncthreads();
    unsigned short* dst = Tt + (size_t)w0 * K_TOT + l * 512 + i0;
#pragma unroll
    for (int r = 0; r < 4; ++r) {
        int w = ty + r * 8;
        dst[(size_t)w * K_TOT + tx] = f2bf(tile[tx][w]);
    }
}

// ---------------- kernel 3: GEMM, Bt pre-transposed (path A) ---------------
// C[m][n] = sum_k (dist[m, k>>9] * x[m, k&511]) * Tt[n][k]
// 128x128 tile, BK=64, 4 waves of 64x64 (4x4 frags of 16x16x32 bf16)
__global__ __launch_bounds__(256, 2) void k_gemm_bt(
    const float* __restrict__ x, const float* __restrict__ dist,
    const unsigned short* __restrict__ Tt, float* __restrict__ part,
    int kchunk)
{
    __shared__ unsigned short As[128][72];   // [m][k], +8 pad
    __shared__ unsigned short Bs[128][64];   // [n][k], xor-swizzled 16B chunks

    const int bm0 = blockIdx.x * 128;
    const int bn0 = blockIdx.y * 128;
    const int kbase = blockIdx.z * kchunk;

    const int lane = threadIdx.x & 63;
    const int wid  = threadIdx.x >> 6;
    const int wm = wid >> 1, wn = wid & 1;
    const int lq = lane >> 4, lr = lane & 15;

    f32x4 acc[4][4];
#pragma unroll
    for (int a = 0; a < 4; ++a)
#pragma unroll
        for (int b = 0; b < 4; ++b)
            acc[a][b] = (f32x4){0.f, 0.f, 0.f, 0.f};

    const int iters = kchunk / 64;
    for (int it = 0; it < iters; ++it) {
        const int k0 = kbase + it * 64;
        const int l  = k0 >> 9;
        const int i0 = k0 & 511;

        // stage A: 128x64, dist-scaled x, bf16
#pragma unroll
        for (int r2 = 0; r2 < 8; ++r2) {
            int id = threadIdx.x + r2 * 256;
            int m  = id >> 4;
            int kc = id & 15;
            float sc = dist[(size_t)(bm0 + m) * N_BINS + l];
            f32x4 v = *(const f32x4*)(x + (size_t)(bm0 + m) * D_DIM + i0 + kc * 4);
            v *= sc;
            unsigned int p0 = (unsigned int)f2bf(v.x) | ((unsigned int)f2bf(v.y) << 16);
            unsigned int p1 = (unsigned int)f2bf(v.z) | ((unsigned int)f2bf(v.w) << 16);
            unsigned int* dp = (unsigned int*)&As[m][kc * 4];
            dp[0] = p0; dp[1] = p1;
        }
        // stage B: 128 rows(n) x 64 k bf16, 16B chunks xor-swizzled
#pragma unroll
        for (int r2 = 0; r2 < 4; ++r2) {
            int id = threadIdx.x + r2 * 256;  // 0..1023
            int n  = id >> 3;
            int c  = id & 7;
            int cg = c ^ (n & 7);
            const u16x8 v = *(const u16x8*)(Tt + (size_t)(bn0 + n) * K_TOT + k0 + cg * 8);
            *(u16x8*)&Bs[n][c * 8] = v;
        }
        __syncthreads();

#pragma unroll
        for (int ks = 0; ks < 2; ++ks) {
            bf16x8 af[4], bfr[4];
#pragma unroll
            for (int fm = 0; fm < 4; ++fm)
                af[fm] = *(const bf16x8*)&As[wm * 64 + fm * 16 + lr][ks * 32 + lq * 8];
#pragma unroll
            for (int fn = 0; fn < 4; ++fn) {
                int nl = wn * 64 + fn * 16 + lr;
                int cs = (ks * 4 + lq) ^ (nl & 7);
                bfr[fn] = *(const bf16x8*)&Bs[nl][cs * 8];
            }
#pragma unroll
            for (int fm = 0; fm < 4; ++fm)
#pragma unroll
                for (int fn = 0; fn < 4; ++fn)
                    acc[fm][fn] = __builtin_amdgcn_mfma_f32_16x16x32_bf16(
                        af[fm], bfr[fn], acc[fm][fn], 0, 0, 0);
        }
        __syncthreads();
    }

    float* Cp = part + (size_t)blockIdx.z * (B_ROWS * W_DIM);
#pragma unroll
    for (int fm = 0; fm < 4; ++fm)
#pragma unroll
        for (int fn = 0; fn < 4; ++fn)
#pragma unroll
            for (int r = 0; r < 4; ++r) {
                int row = bm0 + wm * 64 + fm * 16 + lq * 4 + r;
                int col = bn0 + wn * 64 + fn * 16 + lr;
                Cp[(size_t)row * W_DIM + col] = acc[fm][fn][r];
            }
}

// ---------------- kernel 4: split-K reduction ------------------------------
__global__ __launch_bounds__(256) void k_reduce(
    const float* __restrict__ part, float* __restrict__ out, int nsplit)
{
    int i = (blockIdx.x * 256 + threadIdx.x) * 4;
    f32x4 s = *(const f32x4*)(part + i);
    for (int p = 1; p < nsplit; ++p)
        s += *(const f32x4*)(part + (size_t)p * (B_ROWS * W_DIM) + i);
    *(f32x4*)(out + i) = s;
}

// ---------------- fallback GEMM (ws too small for Tt): in-kernel transpose -
__global__ __launch_bounds__(256, 2) void k_gemm_fb(
    const float* __restrict__ x, const float* __restrict__ dist,
    const float* __restrict__ T, float* __restrict__ out)
{
    __shared__ unsigned short As[128][72];
    __shared__ unsigned short Bs[128][72];

    const int bm0 = blockIdx.x * 128;
    const int bn0 = blockIdx.y * 128;
    const int lane = threadIdx.x & 63;
    const int wid  = threadIdx.x >> 6;
    const int wm = wid >> 1, wn = wid & 1;
    const int lq = lane >> 4, lr = lane & 15;

    f32x4 acc[4][4];
#pragma unroll
    for (int a = 0; a < 4; ++a)
#pragma unroll
        for (int b = 0; b < 4; ++b)
            acc[a][b] = (f32x4){0.f, 0.f, 0.f, 0.f};

    for (int it = 0; it < K_TOT / 64; ++it) {
        const int k0 = it * 64;
        const int l  = k0 >> 9;
        const int i0 = k0 & 511;
#pragma unroll
        for (int r2 = 0; r2 < 8; ++r2) {
            int id = threadIdx.x + r2 * 256;
            int m  = id >> 4;
            int kc = id & 15;
            float sc = dist[(size_t)(bm0 + m) * N_BINS + l];
            f32x4 v = *(const f32x4*)(x + (size_t)(bm0 + m) * D_DIM + i0 + kc * 4);
            v *= sc;
            unsigned int p0 = (unsigned int)f2bf(v.x) | ((unsigned int)f2bf(v.y) << 16);
            unsigned int p1 = (unsigned int)f2bf(v.z) | ((unsigned int)f2bf(v.w) << 16);
            unsigned int* dp = (unsigned int*)&As[m][kc * 4];
            dp[0] = p0; dp[1] = p1;
        }
        // B: read T[k][n] f32 coalesced, scalar-transpose into Bs[n][k]
#pragma unroll
        for (int r2 = 0; r2 < 8; ++r2) {
            int id = threadIdx.x + r2 * 256;   // 0..2047
            int k  = id >> 5;                  // 0..63
            int n4 = (id & 31) * 4;
            f32x4 v = *(const f32x4*)(T + ((size_t)(l * 512 + i0 + k)) * 512 + bn0 + n4);
            Bs[n4 + 0][k] = f2bf(v.x);
            Bs[n4 + 1][k] = f2bf(v.y);
            Bs[n4 + 2][k] = f2bf(v.z);
            Bs[n4 + 3][k] = f2bf(v.w);
        }
        __syncthreads();
#pragma unroll
        for (int ks = 0; ks < 2; ++ks) {
            bf16x8 af[4], bfr[4];
#pragma unroll
            for (int fm = 0; fm < 4; ++fm)
                af[fm] = *(const bf16x8*)&As[wm * 64 + fm * 16 + lr][ks * 32 + lq * 8];
#pragma unroll
            for (int fn = 0; fn < 4; ++fn)
                bfr[fn] = *(const bf16x8*)&Bs[wn * 64 + fn * 16 + lr][ks * 32 + lq * 8];
#pragma unroll
            for (int fm = 0; fm < 4; ++fm)
#pragma unroll
                for (int fn = 0; fn < 4; ++fn)
                    acc[fm][fn] = __builtin_amdgcn_mfma_f32_16x16x32_bf16(
                        af[fm], bfr[fn], acc[fm][fn], 0, 0, 0);
        }
        __syncthreads();
    }
#pragma unroll
    for (int fm = 0; fm < 4; ++fm)
#pragma unroll
        for (int fn = 0; fn < 4; ++fn)
#pragma unroll
            for (int r = 0; r < 4; ++r) {
                int row = bm0 + wm * 64 + fm * 16 + lq * 4 + r;
                int col = bn0 + wn * 64 + fn * 16 + lr;
                out[(size_t)row * W_DIM + col] = acc[fm][fn][r];
            }
}

extern "C" void kernel_launch(void* const* d_in, const int* in_sizes, int n_in,
                              void* d_out, int out_size, void* d_ws, size_t ws_size,
                              hipStream_t stream) {
    const float* x   = (const float*)d_in[0];
    const float* ray = (const float*)d_in[1];
    const float* w_i = (const float*)d_in[2];
    const float* b_i = (const float*)d_in[3];
    const float* a_i = (const float*)d_in[4];
    const float* T   = (const float*)d_in[5];
    const int*   idx = (const int*)d_in[6];
    float* out = (float*)d_out;

    char* ws = (char*)d_ws;
    const size_t distBytes = (size_t)B_ROWS * N_BINS * 4;       // 512 KB
    const size_t ttBytes   = (size_t)W_DIM * K_TOT * 2;         // 33.5 MB
    const size_t partBytes = (size_t)B_ROWS * W_DIM * 4;        // 4 MB per split

    float* dist = (float*)ws;
    k_dist<<<B_ROWS / 4, 256, 0, stream>>>(x, ray, w_i, b_i, a_i, idx, dist);

    if (ws_size >= distBytes + ttBytes) {
        unsigned short* Tt = (unsigned short*)(ws + distBytes);
        size_t avail = ws_size - distBytes - ttBytes;
        int nsplit = (int)(avail / partBytes);
        if (nsplit > 8) nsplit = 8;
        if (nsplit < 1) nsplit = 1;
        while (nsplit & (nsplit - 1)) --nsplit;   // round down to pow2

        k_transpose<<<dim3(16, 16, 64), 256, 0, stream>>>(T, Tt);

        float* part = (nsplit > 1) ? (float*)(ws + distBytes + ttBytes) : out;
        k_gemm_bt<<<dim3(16, 4, nsplit), 256, 0, stream>>>(
            x, dist, Tt, part, K_TOT / nsplit);
        if (nsplit > 1)
            k_reduce<<<(B_ROWS * W_DIM) / (256 * 4), 256, 0, stream>>>(part, out, nsplit);
    } else {
        k_gemm_fb<<<dim3(16, 4), 256, 0, stream>>>(x, dist, T, out);
    }
}